// Round 12
// baseline (260.496 us; speedup 1.0000x reference)
//
#include <hip/hip_runtime.h>
#include <stdint.h>

#define N_NODES 100000
#define N_EDGES 1000000
#define NBUCK 98  // ceil(N_NODES / 1024)

typedef __attribute__((ext_vector_type(8))) __bf16 bf16x8;
typedef __attribute__((ext_vector_type(4))) float f32x4;

// ---------- bf16 helpers ----------
static __device__ __forceinline__ float bf2f(unsigned short u) {
    return __uint_as_float(((unsigned int)u) << 16);
}
static __device__ __forceinline__ unsigned short f2bf(float f) {
    unsigned int u = __float_as_uint(f);
    unsigned int r = (u + 0x7FFFu + ((u >> 16) & 1u)) >> 16;  // RNE
    return (unsigned short)r;
}
static __device__ __forceinline__ float4 ld4_half(const unsigned short* p) {
    ushort4 u = *(const ushort4*)p;
    return make_float4(bf2f(u.x), bf2f(u.y), bf2f(u.z), bf2f(u.w));
}
static __device__ __forceinline__ void st4_half(unsigned short* p, float4 f) {
    ushort4 u;
    u.x = f2bf(f.x); u.y = f2bf(f.y); u.z = f2bf(f.z); u.w = f2bf(f.w);
    *(ushort4*)p = u;
}
// pack 8 f32 -> 8 bf16, one 16B store
static __device__ __forceinline__ void st8_half(unsigned short* p, const float* f) {
    int4 u;
    u.x = (int)(((unsigned)f2bf(f[0])) | (((unsigned)f2bf(f[1])) << 16));
    u.y = (int)(((unsigned)f2bf(f[2])) | (((unsigned)f2bf(f[3])) << 16));
    u.z = (int)(((unsigned)f2bf(f[4])) | (((unsigned)f2bf(f[5])) << 16));
    u.w = (int)(((unsigned)f2bf(f[6])) | (((unsigned)f2bf(f[7])) << 16));
    *(int4*)p = u;
}

// ---------- dynamic-dtype external loads (flag: 1 = bf16 memory, 0 = f32) ----------
static __device__ __forceinline__ float ldf(const void* p, size_t i, int bf) {
    return bf ? bf2f(((const unsigned short*)p)[i]) : ((const float*)p)[i];
}
static __device__ __forceinline__ float4 ldf4(const void* p, size_t i, int bf) {
    if (bf) return ld4_half((const unsigned short*)p + i);
    return *(const float4*)((const float*)p + i);
}

// ---------- dtype probe ----------
__global__ __launch_bounds__(256) void detect_kernel(const unsigned short* __restrict__ xs,
                                                     int* __restrict__ flag) {
    __shared__ int sz;
    if (threadIdx.x == 0) sz = 0;
    __syncthreads();
    int z = 0;
    for (int i = threadIdx.x; i < 1024; i += 256) {
        float av = fabsf(bf2f(xs[2 * i]));
        if (!(av <= 1048576.0f) || (av != 0.0f && av < 9.5367431640625e-07f)) z++;
    }
    atomicAdd(&sz, z);
    __syncthreads();
    if (threadIdx.x == 0) *flag = (sz > 256) ? 0 : 1;
}

// ---------- CSR build, bucket-local ----------
__global__ __launch_bounds__(256) void bhist_kernel(const int* __restrict__ dst,
                                                    int* __restrict__ bcount) {
    __shared__ int cnt[NBUCK];
    int tid = threadIdx.x;
    for (int i = tid; i < NBUCK; i += 256) cnt[i] = 0;
    __syncthreads();
    int e0 = blockIdx.x * 4096;
#pragma unroll
    for (int i = 0; i < 16; ++i) {
        int e = e0 + i * 256 + tid;
        if (e < N_EDGES) atomicAdd(&cnt[dst[e] >> 10], 1);
    }
    __syncthreads();
    for (int i = tid; i < NBUCK; i += 256) {
        int c = cnt[i];
        if (c) atomicAdd(&bcount[i], c);
    }
}

__global__ __launch_bounds__(128) void bscan_kernel(const int* __restrict__ bcount,
                                                    int* __restrict__ bstart,
                                                    int* __restrict__ bcursor) {
    __shared__ int sh[128];
    int tid = threadIdx.x;
    int v = (tid < NBUCK) ? bcount[tid] : 0;
    sh[tid] = v;
    __syncthreads();
    for (int off = 1; off < 128; off <<= 1) {
        int t = 0;
        if (tid >= off) t = sh[tid - off];
        __syncthreads();
        if (tid >= off) sh[tid] += t;
        __syncthreads();
    }
    if (tid < NBUCK) {
        int excl = sh[tid] - v;
        bstart[tid] = excl;
        bcursor[tid] = excl;
    }
    if (tid == NBUCK - 1) bstart[NBUCK] = sh[tid];
}

__global__ __launch_bounds__(256) void part_kernel(const int* __restrict__ src,
                                                   const int* __restrict__ dst,
                                                   const void* __restrict__ val,
                                                   int* __restrict__ bcursor,
                                                   int2* __restrict__ part,
                                                   const int* __restrict__ flagp) {
    __shared__ int cnt[NBUCK];
    __shared__ int base[NBUCK];
    const int bf = *flagp;
    const int tid = threadIdx.x;
    const int e0 = blockIdx.x * 2048;
    for (int i = tid; i < NBUCK; i += 256) cnt[i] = 0;
    __syncthreads();
    int rank[8], bkt[8], pk[8], vb[8];
#pragma unroll
    for (int i = 0; i < 8; ++i) {
        int e = e0 + i * 256 + tid;
        bkt[i] = -1;
        if (e < N_EDGES) {
            int d = dst[e];
            int b = d >> 10;
            bkt[i] = b;
            pk[i] = src[e] | ((d & 1023) << 17);
            vb[i] = __float_as_int(ldf(val, e, bf));
            rank[i] = atomicAdd(&cnt[b], 1);
        }
    }
    __syncthreads();
    for (int i = tid; i < NBUCK; i += 256) {
        int c = cnt[i];
        base[i] = c ? atomicAdd(&bcursor[i], c) : 0;
    }
    __syncthreads();
#pragma unroll
    for (int i = 0; i < 8; ++i) {
        if (bkt[i] >= 0) part[(size_t)base[bkt[i]] + rank[i]] = make_int2(pk[i], vb[i]);
    }
}

__global__ __launch_bounds__(512) void place_kernel(const int* __restrict__ bstart,
                                                    const int2* __restrict__ part,
                                                    int* __restrict__ row_start,
                                                    int2* __restrict__ csr_rec) {
    __shared__ int cnt[1024];
    __shared__ int sums[512];
    const int tid = threadIdx.x;
    const int b = blockIdx.x;
    const int row0 = b << 10;
    const int nrows = min(1024, N_NODES - row0);
    const int s = bstart[b], e = bstart[b + 1];

    for (int i = tid; i < 1024; i += 512) cnt[i] = 0;
    __syncthreads();
    for (int j = s + tid; j < e; j += 512) {
        unsigned p = (unsigned)part[j].x;
        atomicAdd(&cnt[p >> 17], 1);
    }
    __syncthreads();
    int a0 = cnt[2 * tid], a1 = cnt[2 * tid + 1];
    int ts = a0 + a1;
    sums[tid] = ts;
    __syncthreads();
    for (int off = 1; off < 512; off <<= 1) {
        int t = 0;
        if (tid >= off) t = sums[tid - off];
        __syncthreads();
        if (tid >= off) sums[tid] += t;
        __syncthreads();
    }
    int excl = sums[tid] - ts;
    cnt[2 * tid] = s + excl;
    cnt[2 * tid + 1] = s + excl + a0;
    if (2 * tid < nrows)     row_start[row0 + 2 * tid] = s + excl;
    if (2 * tid + 1 < nrows) row_start[row0 + 2 * tid + 1] = s + excl + a0;
    if (b == NBUCK - 1 && tid == 0) row_start[N_NODES] = e;
    __syncthreads();
    for (int j = s + tid; j < e; j += 512) {
        int2 r = part[j];
        unsigned p = (unsigned)r.x;
        int pos = atomicAdd(&cnt[p >> 17], 1);
        csr_rec[pos] = make_int2((int)(p & 0x1FFFFu), r.y);
    }
}

// ---------- wide-load gathers: 8 bf16 cols per lane via one 16B int4 load ----------
// bf16 pair decode: low = u<<16, high = u & 0xffff0000 (both free).

// 2 consecutive dst rows per lane group (64-col support, stride 64 elems)
static __device__ __forceinline__ void duo_gather64(const unsigned short* __restrict__ supc,
                                                    const int2* __restrict__ csr_rec,
                                                    int s, int b1, int e,
                                                    float a0[8], float a1[8]) {
    if (s >= e) return;
    int2 r[8];
#pragma unroll
    for (int t = 0; t < 8; ++t) r[t] = csr_rec[min(s + t, e - 1)];
    for (int j = s; j < e; j += 8) {
        int4 sp[8];
#pragma unroll
        for (int t = 0; t < 8; ++t) sp[t] = *(const int4*)(supc + (size_t)r[t].x * 64);
        float wv[8];
#pragma unroll
        for (int t = 0; t < 8; ++t) wv[t] = (j + t < e) ? __int_as_float(r[t].y) : 0.0f;
        int jn = j + 8;
        if (jn < e) {
#pragma unroll
            for (int t = 0; t < 8; ++t) r[t] = csr_rec[min(jn + t, e - 1)];
        }
#pragma unroll
        for (int t = 0; t < 8; ++t) {
            float w0 = (j + t < b1) ? wv[t] : 0.0f;   // row-0 mask (exact)
            float w1 = wv[t] - w0;                    // row-1 weight (exact)
            int q[4] = {sp[t].x, sp[t].y, sp[t].z, sp[t].w};
#pragma unroll
            for (int c = 0; c < 4; ++c) {
                float flo = __uint_as_float(((unsigned)q[c]) << 16);
                float fhi = __uint_as_float(((unsigned)q[c]) & 0xffff0000u);
                a0[2 * c]     += w0 * flo; a0[2 * c + 1] += w0 * fhi;
                a1[2 * c]     += w1 * flo; a1[2 * c + 1] += w1 * fhi;
            }
        }
    }
}

// 4 consecutive dst rows per lane group (16-col support, stride 16 elems)
static __device__ __forceinline__ void quad_gather16(const unsigned short* __restrict__ supc,
                                                     const int2* __restrict__ csr_rec,
                                                     int s, int b1, int b2, int b3, int e,
                                                     float a[4][8]) {
    if (s >= e) return;
    int2 r[8];
#pragma unroll
    for (int t = 0; t < 8; ++t) r[t] = csr_rec[min(s + t, e - 1)];
    for (int j = s; j < e; j += 8) {
        int4 sp[8];
#pragma unroll
        for (int t = 0; t < 8; ++t) sp[t] = *(const int4*)(supc + (size_t)r[t].x * 16);
        float wv[8];
#pragma unroll
        for (int t = 0; t < 8; ++t) wv[t] = (j + t < e) ? __int_as_float(r[t].y) : 0.0f;
        int jn = j + 8;
        if (jn < e) {
#pragma unroll
            for (int t = 0; t < 8; ++t) r[t] = csr_rec[min(jn + t, e - 1)];
        }
#pragma unroll
        for (int t = 0; t < 8; ++t) {
            int idx = j + t;
            float c0 = (idx < b1) ? wv[t] : 0.0f;
            float c1 = (idx < b2) ? wv[t] : 0.0f;
            float c2 = (idx < b3) ? wv[t] : 0.0f;
            float w0 = c0, w1 = c1 - c0, w2 = c2 - c1, w3 = wv[t] - c2;
            int q[4] = {sp[t].x, sp[t].y, sp[t].z, sp[t].w};
#pragma unroll
            for (int c = 0; c < 4; ++c) {
                float flo = __uint_as_float(((unsigned)q[c]) << 16);
                float fhi = __uint_as_float(((unsigned)q[c]) & 0xffff0000u);
                a[0][2 * c] += w0 * flo; a[0][2 * c + 1] += w0 * fhi;
                a[1][2 * c] += w1 * flo; a[1][2 * c + 1] += w1 * fhi;
                a[2][2 * c] += w2 * flo; a[2][2 * c + 1] += w2 * fhi;
                a[3][2 * c] += w3 * flo; a[3][2 * c + 1] += w3 * fhi;
            }
        }
    }
}

// ---------- MFMA GEMM (layer 1): A direct from global, B read from LDS ----------
template <int K, int M, bool DYNIN>
__global__ __launch_bounds__(256, 4) void mgemm_kernel(const void* __restrict__ hv_,
                                                       const void* __restrict__ W,
                                                       unsigned short* __restrict__ out,
                                                       const int* __restrict__ flagp) {
    constexpr int KP = K + 8;
    constexpr int NC = M / 16;
    constexpr int NK = K / 32;
    constexpr int NT = (N_NODES + 63) / 64;

    __shared__ unsigned short wt[M][KP];  // W transposed

    const int bf = *flagp;
    const int tid = threadIdx.x;

    for (int i = tid; i < K * M; i += 256) {
        int k = i / M, m = i % M;
        wt[m][k] = f2bf(ldf(W, i, bf));
    }
    __syncthreads();

    const int lane = tid & 63;
    const int qd = lane >> 4;
    const int ln = lane & 15;
    const int wrow = (tid >> 6) * 16;

    for (int tile = blockIdx.x; tile < NT; tile += gridDim.x) {
        const int row = tile * 64 + wrow + ln;
        const bool ok = row < N_NODES;

        f32x4 acc[NC];
#pragma unroll
        for (int c = 0; c < NC; ++c) acc[c] = (f32x4){0.f, 0.f, 0.f, 0.f};

#pragma unroll
        for (int ks = 0; ks < NK; ++ks) {
            bf16x8 a;
            if (ok) {
                const size_t base = (size_t)row * K + ks * 32 + qd * 8;
                if (DYNIN && !bf) {
                    const float* xp = (const float*)hv_ + base;
                    float4 f0 = *(const float4*)xp;
                    float4 f1 = *(const float4*)(xp + 4);
                    ushort4 uu[2];
                    uu[0].x = f2bf(f0.x); uu[0].y = f2bf(f0.y); uu[0].z = f2bf(f0.z); uu[0].w = f2bf(f0.w);
                    uu[1].x = f2bf(f1.x); uu[1].y = f2bf(f1.y); uu[1].z = f2bf(f1.z); uu[1].w = f2bf(f1.w);
                    a = *(const bf16x8*)uu;
                } else {
                    a = *(const bf16x8*)((const unsigned short*)hv_ + base);
                }
            } else {
                a = (bf16x8)(__bf16)0.0f;
            }
#pragma unroll
            for (int c = 0; c < NC; ++c) {
                bf16x8 b = *(const bf16x8*)&wt[c * 16 + ln][ks * 32 + qd * 8];
                acc[c] = __builtin_amdgcn_mfma_f32_16x16x32_bf16(a, b, acc[c], 0, 0, 0);
            }
        }

#pragma unroll
        for (int c = 0; c < NC; ++c) {
#pragma unroll
            for (int r = 0; r < 4; ++r) {
                int orow = tile * 64 + wrow + qd * 4 + r;
                if (orow < N_NODES) out[(size_t)orow * M + c * 16 + ln] = f2bf(acc[c][r]);
            }
        }
    }
}

// ---------- Fused: agg = relu(spmm(support)+bias); out = agg @ W  (K=64 fixed) ----------
// Gather: 32 groups x 8 lanes; each lane loads 16B (8 cols); group owns 2 dst rows.
template <int MOUT>
__global__ __launch_bounds__(256) void fused_kernel(const unsigned short* __restrict__ support,
                                                    const int* __restrict__ row_start,
                                                    const int2* __restrict__ csr_rec,
                                                    const void* __restrict__ bias,
                                                    const void* __restrict__ W,
                                                    unsigned short* __restrict__ out,
                                                    const int* __restrict__ flagp) {
    constexpr int K = 64, KP = 72;
    constexpr int NC = MOUT / 16;
    constexpr int NK = 2;
    constexpr int NT = (N_NODES + 63) / 64;

    __shared__ unsigned short agg[64][KP];
    __shared__ unsigned short wt[MOUT][KP];

    const int bf = *flagp;
    const int tid = threadIdx.x;

    for (int i = tid; i < K * MOUT; i += 256) {
        int k = i / MOUT, m = i % MOUT;
        wt[m][k] = f2bf(ldf(W, i, bf));
    }
    __syncthreads();

    const int lane = tid & 63;
    const int qd = lane >> 4;
    const int ln = lane & 15;
    const int wrow = (tid >> 6) * 16;

    const int grp = tid >> 3;   // 32 groups of 8 lanes; 2 rows each
    const int cc = tid & 7;     // cols cc*8..cc*8+7
    float bias8[8];
#pragma unroll
    for (int c = 0; c < 8; ++c) bias8[c] = ldf(bias, cc * 8 + c, bf);
    const unsigned short* supc = support + cc * 8;

    for (int tile = blockIdx.x; tile < NT; tile += gridDim.x) {
        const int r0 = tile * 64 + grp * 2;
        int s  = row_start[min(r0 + 0, N_NODES)];
        int b1 = row_start[min(r0 + 1, N_NODES)];
        int e  = row_start[min(r0 + 2, N_NODES)];

        float a0[8], a1[8];
#pragma unroll
        for (int c = 0; c < 8; ++c) { a0[c] = bias8[c]; a1[c] = bias8[c]; }
        duo_gather64(supc, csr_rec, s, b1, e, a0, a1);
#pragma unroll
        for (int c = 0; c < 8; ++c) {
            a0[c] = fmaxf(a0[c], 0.f);
            a1[c] = fmaxf(a1[c], 0.f);
        }
        st8_half(&agg[grp * 2 + 0][cc * 8], a0);
        st8_half(&agg[grp * 2 + 1][cc * 8], a1);
        __syncthreads();

        f32x4 macc[NC];
#pragma unroll
        for (int c = 0; c < NC; ++c) macc[c] = (f32x4){0.f, 0.f, 0.f, 0.f};
#pragma unroll
        for (int ks = 0; ks < NK; ++ks) {
            bf16x8 a = *(const bf16x8*)&agg[wrow + ln][ks * 32 + qd * 8];
#pragma unroll
            for (int c = 0; c < NC; ++c) {
                bf16x8 b = *(const bf16x8*)&wt[c * 16 + ln][ks * 32 + qd * 8];
                macc[c] = __builtin_amdgcn_mfma_f32_16x16x32_bf16(a, b, macc[c], 0, 0, 0);
            }
        }

#pragma unroll
        for (int c = 0; c < NC; ++c) {
#pragma unroll
            for (int r = 0; r < 4; ++r) {
                int orow = tile * 64 + wrow + qd * 4 + r;
                if (orow < N_NODES) out[(size_t)orow * MOUT + c * 16 + ln] = f2bf(macc[c][r]);
            }
        }
        __syncthreads();  // agg reused next tile
    }
}

// ---------- final SpMM (M=16): 2 lanes x 16B per row, 4 rows per group ----------
template <bool DYNOUT>
__global__ __launch_bounds__(256) void spmm16_kernel(const unsigned short* __restrict__ support,
                                                     const int* __restrict__ row_start,
                                                     const int2* __restrict__ csr_rec,
                                                     const void* __restrict__ bias,
                                                     void* __restrict__ out_,
                                                     const int* __restrict__ flagp) {
    constexpr int M = 16;
    int bf = *flagp;
    int tid = threadIdx.x;
    int grp = tid >> 1;           // 128 groups x 4 rows = 512 rows per block
    int cc = tid & 1;             // cols cc*8..cc*8+7
    int r0 = blockIdx.x * 512 + grp * 4;
    if (r0 >= N_NODES) return;
    int s  = row_start[min(r0 + 0, N_NODES)];
    int b1 = row_start[min(r0 + 1, N_NODES)];
    int b2 = row_start[min(r0 + 2, N_NODES)];
    int b3 = row_start[min(r0 + 3, N_NODES)];
    int e  = row_start[min(r0 + 4, N_NODES)];
    float a[4][8];
#pragma unroll
    for (int k = 0; k < 4; ++k)
#pragma unroll
        for (int c = 0; c < 8; ++c) a[k][c] = ldf(bias, cc * 8 + c, bf);
    quad_gather16(support + cc * 8, csr_rec, s, b1, b2, b3, e, a);
#pragma unroll
    for (int k = 0; k < 4; ++k) {
        int row = r0 + k;
        if (row < N_NODES) {
            if (DYNOUT && !bf) {
                float* op = (float*)out_ + (size_t)row * M + cc * 8;
                *(float4*)op = make_float4(a[k][0], a[k][1], a[k][2], a[k][3]);
                *(float4*)(op + 4) = make_float4(a[k][4], a[k][5], a[k][6], a[k][7]);
            } else {
                st8_half((unsigned short*)out_ + (size_t)row * M + cc * 8, a[k]);
            }
        }
    }
}

extern "C" void kernel_launch(void* const* d_in, const int* in_sizes, int n_in,
                              void* d_out, int out_size, void* d_ws, size_t ws_size,
                              hipStream_t stream) {
    (void)in_sizes; (void)n_in; (void)out_size; (void)ws_size;
    const void* x  = d_in[0];
    const void* ev = d_in[1];
    const void* W1 = d_in[2];
    const void* b1 = d_in[3];
    const void* W2 = d_in[4];
    const void* b2 = d_in[5];
    const void* W3 = d_in[6];
    const void* b3 = d_in[7];
    const int* esrc = (const int*)d_in[8];
    const int* edst = (const int*)d_in[9];

    // workspace (~34 MB)
    char* ws = (char*)d_ws;
    size_t off = 0;
    auto alloc = [&](size_t bytes) -> void* {
        void* p = ws + off;
        off = (off + bytes + 255) & ~(size_t)255;
        return p;
    };
    unsigned short* A = (unsigned short*)alloc((size_t)N_NODES * 64 * 2);  // support1 / A3
    unsigned short* B = (unsigned short*)alloc((size_t)N_NODES * 64 * 2);  // A2
    int* row_start  = (int*)alloc((size_t)(N_NODES + 1) * 4);
    int* bcount     = (int*)alloc(512);
    int* bstart     = (int*)alloc(512);
    int* bcursor    = (int*)alloc(512);
    int2* csr_rec   = (int2*)alloc((size_t)N_EDGES * 8);
    int* flagp      = (int*)alloc(256);
    // part[] (8 MB) aliases A (12.8 MB): dead before mgemm1 writes A
    int2* part      = (int2*)A;

    // ---- dtype probe ----
    detect_kernel<<<1, 256, 0, stream>>>((const unsigned short*)x, flagp);

    // ---- bucket-local CSR build ----
    hipMemsetAsync(bcount, 0, 512, stream);
    bhist_kernel<<<(N_EDGES + 4095) / 4096, 256, 0, stream>>>(edst, bcount);
    bscan_kernel<<<1, 128, 0, stream>>>(bcount, bstart, bcursor);
    part_kernel<<<(N_EDGES + 2047) / 2048, 256, 0, stream>>>(esrc, edst, ev, bcursor, part, flagp);
    place_kernel<<<NBUCK, 512, 0, stream>>>(bstart, part, row_start, csr_rec);

    const int NT = (N_NODES + 63) / 64;  // 1563

    // ---- layer 1: A = x @ W1 ----
    mgemm_kernel<128, 64, true><<<1024, 256, 0, stream>>>(x, W1, A, flagp);
    // ---- layer 1 agg + layer 2 gemm fused: B = relu(spmm(A)+b1) @ W2 ----
    fused_kernel<64><<<NT, 256, 0, stream>>>(A, row_start, csr_rec, b1, W2, B, flagp);
    // ---- layer 2 agg + layer 3 gemm fused: A(=A3) = relu(spmm(B)+b2) @ W3 ----
    fused_kernel<16><<<NT, 256, 0, stream>>>(B, row_start, csr_rec, b2, W3, A, flagp);
    // ---- final aggregation: out = spmm(A3) + b3 ----
    spmm16_kernel<true><<<(N_NODES + 511) / 512, 256, 0, stream>>>(A, row_start, csr_rec, b3, d_out, flagp);
}

// Round 13
// 244.791 us; speedup vs baseline: 1.0642x; 1.0642x over previous
//
#include <hip/hip_runtime.h>
#include <stdint.h>

#define N_NODES 100000
#define N_EDGES 1000000
#define NBUCK 98    // ceil(N_NODES / 1024)
#define CAP 12288   // per-bucket part capacity; counts ~ Poisson(10240), +20 sigma

typedef __attribute__((ext_vector_type(8))) __bf16 bf16x8;
typedef __attribute__((ext_vector_type(4))) float f32x4;

// ---------- bf16 helpers ----------
static __device__ __forceinline__ float bf2f(unsigned short u) {
    return __uint_as_float(((unsigned int)u) << 16);
}
static __device__ __forceinline__ unsigned short f2bf(float f) {
    unsigned int u = __float_as_uint(f);
    unsigned int r = (u + 0x7FFFu + ((u >> 16) & 1u)) >> 16;  // RNE
    return (unsigned short)r;
}
static __device__ __forceinline__ float4 ld4_half(const unsigned short* p) {
    ushort4 u = *(const ushort4*)p;
    return make_float4(bf2f(u.x), bf2f(u.y), bf2f(u.z), bf2f(u.w));
}
static __device__ __forceinline__ void st4_half(unsigned short* p, float4 f) {
    ushort4 u;
    u.x = f2bf(f.x); u.y = f2bf(f.y); u.z = f2bf(f.z); u.w = f2bf(f.w);
    *(ushort4*)p = u;
}
// pack 8 f32 -> 8 bf16, one 16B store
static __device__ __forceinline__ void st8_half(unsigned short* p, const float* f) {
    int4 u;
    u.x = (int)(((unsigned)f2bf(f[0])) | (((unsigned)f2bf(f[1])) << 16));
    u.y = (int)(((unsigned)f2bf(f[2])) | (((unsigned)f2bf(f[3])) << 16));
    u.z = (int)(((unsigned)f2bf(f[4])) | (((unsigned)f2bf(f[5])) << 16));
    u.w = (int)(((unsigned)f2bf(f[6])) | (((unsigned)f2bf(f[7])) << 16));
    *(int4*)p = u;
}

// ---------- dynamic-dtype external loads (flag: 1 = bf16 memory, 0 = f32) ----------
static __device__ __forceinline__ float ldf(const void* p, size_t i, int bf) {
    return bf ? bf2f(((const unsigned short*)p)[i]) : ((const float*)p)[i];
}
static __device__ __forceinline__ float4 ldf4(const void* p, size_t i, int bf) {
    if (bf) return ld4_half((const unsigned short*)p + i);
    return *(const float4*)((const float*)p + i);
}

// ---------- dtype probe + cursor init ----------
__global__ __launch_bounds__(256) void detect_kernel(const unsigned short* __restrict__ xs,
                                                     int* __restrict__ flag,
                                                     int* __restrict__ bcursor) {
    __shared__ int sz;
    if (threadIdx.x == 0) sz = 0;
    __syncthreads();
    int z = 0;
    for (int i = threadIdx.x; i < 1024; i += 256) {
        float av = fabsf(bf2f(xs[2 * i]));
        if (!(av <= 1048576.0f) || (av != 0.0f && av < 9.5367431640625e-07f)) z++;
    }
    atomicAdd(&sz, z);
    if (threadIdx.x < NBUCK) bcursor[threadIdx.x] = threadIdx.x * CAP;
    __syncthreads();
    if (threadIdx.x == 0) *flag = (sz > 256) ? 0 : 1;
}

// ---------- partition edges into fixed-capacity bucket regions ----------
// rec = {src | dst_local<<17, val_bits}; region b = part[b*CAP ...)
__global__ __launch_bounds__(256) void part_kernel(const int* __restrict__ src,
                                                   const int* __restrict__ dst,
                                                   const void* __restrict__ val,
                                                   int* __restrict__ bcursor,
                                                   int2* __restrict__ part,
                                                   const int* __restrict__ flagp) {
    __shared__ int cnt[NBUCK];
    __shared__ int base[NBUCK];
    const int bf = *flagp;
    const int tid = threadIdx.x;
    const int e0 = blockIdx.x * 2048;
    for (int i = tid; i < NBUCK; i += 256) cnt[i] = 0;
    __syncthreads();
    int rank[8], bkt[8], pk[8], vb[8];
#pragma unroll
    for (int i = 0; i < 8; ++i) {
        int e = e0 + i * 256 + tid;
        bkt[i] = -1;
        if (e < N_EDGES) {
            int d = dst[e];
            int b = d >> 10;
            bkt[i] = b;
            pk[i] = src[e] | ((d & 1023) << 17);
            vb[i] = __float_as_int(ldf(val, e, bf));
            rank[i] = atomicAdd(&cnt[b], 1);
        }
    }
    __syncthreads();
    for (int i = tid; i < NBUCK; i += 256) {
        int c = cnt[i];
        base[i] = c ? atomicAdd(&bcursor[i], c) : 0;
    }
    __syncthreads();
#pragma unroll
    for (int i = 0; i < 8; ++i) {
        if (bkt[i] >= 0) part[(size_t)base[bkt[i]] + rank[i]] = make_int2(pk[i], vb[i]);
    }
}

// ---------- place: per-bucket row histogram+scan, compact csr_rec + row_start ----------
// Each block redundantly prefix-scans the 98 bucket counts (from bcursor) itself.
__global__ __launch_bounds__(512) void place_kernel(const int* __restrict__ bcursor,
                                                    const int2* __restrict__ part,
                                                    int* __restrict__ row_start,
                                                    int2* __restrict__ csr_rec) {
    __shared__ int cnt[1024];
    __shared__ int sums[512];
    __shared__ int sh_s, sh_cnt, sh_total;
    const int tid = threadIdx.x;
    const int b = blockIdx.x;
    const int row0 = b << 10;
    const int nrows = min(1024, N_NODES - row0);

    // bucket-count exclusive prefix (redundant, trivial)
    if (tid < 128) sums[tid] = (tid < NBUCK) ? (bcursor[tid] - tid * CAP) : 0;
    __syncthreads();
    for (int off = 1; off < 128; off <<= 1) {
        int t = 0;
        if (tid < 128 && tid >= off) t = sums[tid - off];
        __syncthreads();
        if (tid < 128 && tid >= off) sums[tid] += t;
        __syncthreads();
    }
    if (tid == 0) {
        sh_s = (b > 0) ? sums[b - 1] : 0;
        sh_cnt = bcursor[b] - b * CAP;
        sh_total = sums[NBUCK - 1];
    }
    __syncthreads();
    const int s = sh_s;          // global csr_rec start of this bucket
    const int cb = sh_cnt;       // edges in this bucket
    const int ps = b * CAP;      // part region start
    const int total = sh_total;

    for (int i = tid; i < 1024; i += 512) cnt[i] = 0;
    __syncthreads();
    for (int j = tid; j < cb; j += 512) {
        unsigned p = (unsigned)part[ps + j].x;
        atomicAdd(&cnt[p >> 17], 1);
    }
    __syncthreads();
    int a0 = cnt[2 * tid], a1 = cnt[2 * tid + 1];
    int ts = a0 + a1;
    sums[tid] = ts;
    __syncthreads();
    for (int off = 1; off < 512; off <<= 1) {
        int t = 0;
        if (tid >= off) t = sums[tid - off];
        __syncthreads();
        if (tid >= off) sums[tid] += t;
        __syncthreads();
    }
    int excl = sums[tid] - ts;
    cnt[2 * tid] = s + excl;          // running cursors (global positions)
    cnt[2 * tid + 1] = s + excl + a0;
    if (2 * tid < nrows)     row_start[row0 + 2 * tid] = s + excl;
    if (2 * tid + 1 < nrows) row_start[row0 + 2 * tid + 1] = s + excl + a0;
    if (b == NBUCK - 1 && tid == 0) row_start[N_NODES] = total;
    __syncthreads();
    for (int j = tid; j < cb; j += 512) {
        int2 r = part[ps + j];
        unsigned p = (unsigned)r.x;
        int pos = atomicAdd(&cnt[p >> 17], 1);
        csr_rec[pos] = make_int2((int)(p & 0x1FFFFu), r.y);
    }
}

// ---------- wide-load gathers: 8 bf16 cols per lane via one 16B int4 load ----------
static __device__ __forceinline__ void duo_gather64(const unsigned short* __restrict__ supc,
                                                    const int2* __restrict__ csr_rec,
                                                    int s, int b1, int e,
                                                    float a0[8], float a1[8]) {
    if (s >= e) return;
    int2 r[8];
#pragma unroll
    for (int t = 0; t < 8; ++t) r[t] = csr_rec[min(s + t, e - 1)];
    for (int j = s; j < e; j += 8) {
        int4 sp[8];
#pragma unroll
        for (int t = 0; t < 8; ++t) sp[t] = *(const int4*)(supc + (size_t)r[t].x * 64);
        float wv[8];
#pragma unroll
        for (int t = 0; t < 8; ++t) wv[t] = (j + t < e) ? __int_as_float(r[t].y) : 0.0f;
        int jn = j + 8;
        if (jn < e) {
#pragma unroll
            for (int t = 0; t < 8; ++t) r[t] = csr_rec[min(jn + t, e - 1)];
        }
#pragma unroll
        for (int t = 0; t < 8; ++t) {
            float w0 = (j + t < b1) ? wv[t] : 0.0f;
            float w1 = wv[t] - w0;
            int q[4] = {sp[t].x, sp[t].y, sp[t].z, sp[t].w};
#pragma unroll
            for (int c = 0; c < 4; ++c) {
                float flo = __uint_as_float(((unsigned)q[c]) << 16);
                float fhi = __uint_as_float(((unsigned)q[c]) & 0xffff0000u);
                a0[2 * c]     += w0 * flo; a0[2 * c + 1] += w0 * fhi;
                a1[2 * c]     += w1 * flo; a1[2 * c + 1] += w1 * fhi;
            }
        }
    }
}

static __device__ __forceinline__ void quad_gather16(const unsigned short* __restrict__ supc,
                                                     const int2* __restrict__ csr_rec,
                                                     int s, int b1, int b2, int b3, int e,
                                                     float a[4][8]) {
    if (s >= e) return;
    int2 r[8];
#pragma unroll
    for (int t = 0; t < 8; ++t) r[t] = csr_rec[min(s + t, e - 1)];
    for (int j = s; j < e; j += 8) {
        int4 sp[8];
#pragma unroll
        for (int t = 0; t < 8; ++t) sp[t] = *(const int4*)(supc + (size_t)r[t].x * 16);
        float wv[8];
#pragma unroll
        for (int t = 0; t < 8; ++t) wv[t] = (j + t < e) ? __int_as_float(r[t].y) : 0.0f;
        int jn = j + 8;
        if (jn < e) {
#pragma unroll
            for (int t = 0; t < 8; ++t) r[t] = csr_rec[min(jn + t, e - 1)];
        }
#pragma unroll
        for (int t = 0; t < 8; ++t) {
            int idx = j + t;
            float c0 = (idx < b1) ? wv[t] : 0.0f;
            float c1 = (idx < b2) ? wv[t] : 0.0f;
            float c2 = (idx < b3) ? wv[t] : 0.0f;
            float w0 = c0, w1 = c1 - c0, w2 = c2 - c1, w3 = wv[t] - c2;
            int q[4] = {sp[t].x, sp[t].y, sp[t].z, sp[t].w};
#pragma unroll
            for (int c = 0; c < 4; ++c) {
                float flo = __uint_as_float(((unsigned)q[c]) << 16);
                float fhi = __uint_as_float(((unsigned)q[c]) & 0xffff0000u);
                a[0][2 * c] += w0 * flo; a[0][2 * c + 1] += w0 * fhi;
                a[1][2 * c] += w1 * flo; a[1][2 * c + 1] += w1 * fhi;
                a[2][2 * c] += w2 * flo; a[2][2 * c + 1] += w2 * fhi;
                a[3][2 * c] += w3 * flo; a[3][2 * c + 1] += w3 * fhi;
            }
        }
    }
}

// ---------- MFMA GEMM (layer 1): one 64-row tile per block, A direct from global ----------
template <int K, int M, bool DYNIN>
__global__ __launch_bounds__(256) void mgemm_kernel(const void* __restrict__ hv_,
                                                    const void* __restrict__ W,
                                                    unsigned short* __restrict__ out,
                                                    const int* __restrict__ flagp) {
    constexpr int KP = K + 8;
    constexpr int NC = M / 16;
    constexpr int NK = K / 32;

    __shared__ unsigned short wt[M][KP];  // W transposed

    const int bf = *flagp;
    const int tid = threadIdx.x;

    for (int i = tid; i < K * M; i += 256) {
        int k = i / M, m = i % M;
        wt[m][k] = f2bf(ldf(W, i, bf));
    }
    __syncthreads();

    const int lane = tid & 63;
    const int qd = lane >> 4;
    const int ln = lane & 15;
    const int wrow = (tid >> 6) * 16;
    const int tile = blockIdx.x;

    const int row = tile * 64 + wrow + ln;
    const bool ok = row < N_NODES;

    f32x4 acc[NC];
#pragma unroll
    for (int c = 0; c < NC; ++c) acc[c] = (f32x4){0.f, 0.f, 0.f, 0.f};

#pragma unroll
    for (int ks = 0; ks < NK; ++ks) {
        bf16x8 a;
        if (ok) {
            const size_t base = (size_t)row * K + ks * 32 + qd * 8;
            if (DYNIN && !bf) {
                const float* xp = (const float*)hv_ + base;
                float4 f0 = *(const float4*)xp;
                float4 f1 = *(const float4*)(xp + 4);
                ushort4 uu[2];
                uu[0].x = f2bf(f0.x); uu[0].y = f2bf(f0.y); uu[0].z = f2bf(f0.z); uu[0].w = f2bf(f0.w);
                uu[1].x = f2bf(f1.x); uu[1].y = f2bf(f1.y); uu[1].z = f2bf(f1.z); uu[1].w = f2bf(f1.w);
                a = *(const bf16x8*)uu;
            } else {
                a = *(const bf16x8*)((const unsigned short*)hv_ + base);
            }
        } else {
            a = (bf16x8)(__bf16)0.0f;
        }
#pragma unroll
        for (int c = 0; c < NC; ++c) {
            bf16x8 b = *(const bf16x8*)&wt[c * 16 + ln][ks * 32 + qd * 8];
            acc[c] = __builtin_amdgcn_mfma_f32_16x16x32_bf16(a, b, acc[c], 0, 0, 0);
        }
    }

#pragma unroll
    for (int c = 0; c < NC; ++c) {
#pragma unroll
        for (int r = 0; r < 4; ++r) {
            int orow = tile * 64 + wrow + qd * 4 + r;
            if (orow < N_NODES) out[(size_t)orow * M + c * 16 + ln] = f2bf(acc[c][r]);
        }
    }
}

// ---------- Fused: agg = relu(spmm(support)+bias); out = agg @ W  (K=64 fixed) ----------
template <int MOUT>
__global__ __launch_bounds__(256) void fused_kernel(const unsigned short* __restrict__ support,
                                                    const int* __restrict__ row_start,
                                                    const int2* __restrict__ csr_rec,
                                                    const void* __restrict__ bias,
                                                    const void* __restrict__ W,
                                                    unsigned short* __restrict__ out,
                                                    const int* __restrict__ flagp) {
    constexpr int K = 64, KP = 72;
    constexpr int NC = MOUT / 16;
    constexpr int NK = 2;

    __shared__ unsigned short agg[64][KP];
    __shared__ unsigned short wt[MOUT][KP];

    const int bf = *flagp;
    const int tid = threadIdx.x;

    for (int i = tid; i < K * MOUT; i += 256) {
        int k = i / MOUT, m = i % MOUT;
        wt[m][k] = f2bf(ldf(W, i, bf));
    }
    __syncthreads();

    const int lane = tid & 63;
    const int qd = lane >> 4;
    const int ln = lane & 15;
    const int wrow = (tid >> 6) * 16;

    const int grp = tid >> 3;   // 32 groups of 8 lanes; 2 rows each
    const int cc = tid & 7;     // cols cc*8..cc*8+7
    float bias8[8];
#pragma unroll
    for (int c = 0; c < 8; ++c) bias8[c] = ldf(bias, cc * 8 + c, bf);
    const unsigned short* supc = support + cc * 8;

    const int tile = blockIdx.x;
    const int r0 = tile * 64 + grp * 2;
    int s  = row_start[min(r0 + 0, N_NODES)];
    int b1 = row_start[min(r0 + 1, N_NODES)];
    int e  = row_start[min(r0 + 2, N_NODES)];

    float a0[8], a1[8];
#pragma unroll
    for (int c = 0; c < 8; ++c) { a0[c] = bias8[c]; a1[c] = bias8[c]; }
    duo_gather64(supc, csr_rec, s, b1, e, a0, a1);
#pragma unroll
    for (int c = 0; c < 8; ++c) {
        a0[c] = fmaxf(a0[c], 0.f);
        a1[c] = fmaxf(a1[c], 0.f);
    }
    st8_half(&agg[grp * 2 + 0][cc * 8], a0);
    st8_half(&agg[grp * 2 + 1][cc * 8], a1);
    __syncthreads();

    f32x4 macc[NC];
#pragma unroll
    for (int c = 0; c < NC; ++c) macc[c] = (f32x4){0.f, 0.f, 0.f, 0.f};
#pragma unroll
    for (int ks = 0; ks < NK; ++ks) {
        bf16x8 a = *(const bf16x8*)&agg[wrow + ln][ks * 32 + qd * 8];
#pragma unroll
        for (int c = 0; c < NC; ++c) {
            bf16x8 b = *(const bf16x8*)&wt[c * 16 + ln][ks * 32 + qd * 8];
            macc[c] = __builtin_amdgcn_mfma_f32_16x16x32_bf16(a, b, macc[c], 0, 0, 0);
        }
    }

#pragma unroll
    for (int c = 0; c < NC; ++c) {
#pragma unroll
        for (int r = 0; r < 4; ++r) {
            int orow = tile * 64 + wrow + qd * 4 + r;
            if (orow < N_NODES) out[(size_t)orow * MOUT + c * 16 + ln] = f2bf(macc[c][r]);
        }
    }
}

// ---------- final SpMM (M=16): 2 lanes x 16B per row, 4 rows per group ----------
template <bool DYNOUT>
__global__ __launch_bounds__(256) void spmm16_kernel(const unsigned short* __restrict__ support,
                                                     const int* __restrict__ row_start,
                                                     const int2* __restrict__ csr_rec,
                                                     const void* __restrict__ bias,
                                                     void* __restrict__ out_,
                                                     const int* __restrict__ flagp) {
    constexpr int M = 16;
    int bf = *flagp;
    int tid = threadIdx.x;
    int grp = tid >> 1;           // 128 groups x 4 rows = 512 rows per block
    int cc = tid & 1;             // cols cc*8..cc*8+7
    int r0 = blockIdx.x * 512 + grp * 4;
    if (r0 >= N_NODES) return;
    int s  = row_start[min(r0 + 0, N_NODES)];
    int b1 = row_start[min(r0 + 1, N_NODES)];
    int b2 = row_start[min(r0 + 2, N_NODES)];
    int b3 = row_start[min(r0 + 3, N_NODES)];
    int e  = row_start[min(r0 + 4, N_NODES)];
    float a[4][8];
#pragma unroll
    for (int k = 0; k < 4; ++k)
#pragma unroll
        for (int c = 0; c < 8; ++c) a[k][c] = ldf(bias, cc * 8 + c, bf);
    quad_gather16(support + cc * 8, csr_rec, s, b1, b2, b3, e, a);
#pragma unroll
    for (int k = 0; k < 4; ++k) {
        int row = r0 + k;
        if (row < N_NODES) {
            if (DYNOUT && !bf) {
                float* op = (float*)out_ + (size_t)row * M + cc * 8;
                *(float4*)op = make_float4(a[k][0], a[k][1], a[k][2], a[k][3]);
                *(float4*)(op + 4) = make_float4(a[k][4], a[k][5], a[k][6], a[k][7]);
            } else {
                st8_half((unsigned short*)out_ + (size_t)row * M + cc * 8, a[k]);
            }
        }
    }
}

extern "C" void kernel_launch(void* const* d_in, const int* in_sizes, int n_in,
                              void* d_out, int out_size, void* d_ws, size_t ws_size,
                              hipStream_t stream) {
    (void)in_sizes; (void)n_in; (void)out_size; (void)ws_size;
    const void* x  = d_in[0];
    const void* ev = d_in[1];
    const void* W1 = d_in[2];
    const void* b1 = d_in[3];
    const void* W2 = d_in[4];
    const void* b2 = d_in[5];
    const void* W3 = d_in[6];
    const void* b3 = d_in[7];
    const int* esrc = (const int*)d_in[8];
    const int* edst = (const int*)d_in[9];

    // workspace (~34 MB)
    char* ws = (char*)d_ws;
    size_t off = 0;
    auto alloc = [&](size_t bytes) -> void* {
        void* p = ws + off;
        off = (off + bytes + 255) & ~(size_t)255;
        return p;
    };
    unsigned short* A = (unsigned short*)alloc((size_t)N_NODES * 64 * 2);  // support1 / A3
    unsigned short* B = (unsigned short*)alloc((size_t)N_NODES * 64 * 2);  // A2
    int* row_start  = (int*)alloc((size_t)(N_NODES + 1) * 4);
    int* bcursor    = (int*)alloc(512);
    int2* csr_rec   = (int2*)alloc((size_t)N_EDGES * 8);
    int* flagp      = (int*)alloc(256);
    // part[] (9.6 MB = 98*CAP*8) aliases A (12.8 MB): dead before mgemm1 writes A
    int2* part      = (int2*)A;

    // ---- dtype probe + cursor init ----
    detect_kernel<<<1, 256, 0, stream>>>((const unsigned short*)x, flagp, bcursor);

    // ---- CSR build: partition -> place (compact) ----
    part_kernel<<<(N_EDGES + 2047) / 2048, 256, 0, stream>>>(esrc, edst, ev, bcursor, part, flagp);
    place_kernel<<<NBUCK, 512, 0, stream>>>(bcursor, part, row_start, csr_rec);

    const int NT = (N_NODES + 63) / 64;  // 1563

    // ---- layer 1: A = x @ W1 ----
    mgemm_kernel<128, 64, true><<<NT, 256, 0, stream>>>(x, W1, A, flagp);
    // ---- layer 1 agg + layer 2 gemm fused: B = relu(spmm(A)+b1) @ W2 ----
    fused_kernel<64><<<NT, 256, 0, stream>>>(A, row_start, csr_rec, b1, W2, B, flagp);
    // ---- layer 2 agg + layer 3 gemm fused: A(=A3) = relu(spmm(B)+b2) @ W3 ----
    fused_kernel<16><<<NT, 256, 0, stream>>>(B, row_start, csr_rec, b2, W3, A, flagp);
    // ---- final aggregation: out = spmm(A3) + b3 ----
    spmm16_kernel<true><<<(N_NODES + 511) / 512, 256, 0, stream>>>(A, row_start, csr_rec, b3, d_out, flagp);
}